// Round 10
// baseline (321.243 us; speedup 1.0000x reference)
//
#include <hip/hip_runtime.h>
#include <cstdint>
#include <math.h>

constexpr int NN = 32768;
constexpr int KK = 4096;
constexpr int DD = 256;

typedef __attribute__((ext_vector_type(8))) short short8;
typedef __attribute__((ext_vector_type(4))) float f32x4;

#define AS1 __attribute__((address_space(1)))
#define AS3 __attribute__((address_space(3)))

// async 16B global->LDS: per-lane global src, wave-uniform LDS base (+lane*16 by HW)
__device__ __forceinline__ void gload16(unsigned short* lds_dst, const unsigned short* gsrc) {
  __builtin_amdgcn_global_load_lds((const AS1 unsigned int*)gsrc, (AS3 unsigned int*)lds_dst,
                                   16, 0, 0);
}

// ---------- monotone float<->u32 (order-preserving incl. negatives) ----------
__device__ __forceinline__ unsigned mono(float v) {
  unsigned u = __float_as_uint(v);
  return (u & 0x80000000u) ? ~u : (u | 0x80000000u);
}
__device__ __forceinline__ float unmono(unsigned u) {
  u = (u & 0x80000000u) ? (u & 0x7fffffffu) : ~u;
  return __uint_as_float(u);
}

// ============ numpy-replica row sum-of-squares (verified bit-exact r2) ============
__device__ __forceinline__ void sq16(const float4* __restrict__ p, int b, float q[16]) {
#pragma unroll
  for (int j = 0; j < 4; ++j) {
    const float4 v = p[b * 4 + j];
    q[4 * j + 0] = v.x * v.x;
    q[4 * j + 1] = v.y * v.y;
    q[4 * j + 2] = v.z * v.z;
    q[4 * j + 3] = v.w * v.w;
  }
}
__device__ __forceinline__ float np_pw128_sq(const float4* __restrict__ p, int b0) {
  float A[16], B[16], r01[16], r23[16], q0123[16], r45[16], r67[16];
  sq16(p, b0 + 0, A); sq16(p, b0 + 1, B);
#pragma unroll
  for (int l = 0; l < 16; ++l) r01[l] = A[l] + B[l];
  sq16(p, b0 + 2, A); sq16(p, b0 + 3, B);
#pragma unroll
  for (int l = 0; l < 16; ++l) r23[l] = A[l] + B[l];
#pragma unroll
  for (int l = 0; l < 16; ++l) q0123[l] = r01[l] + r23[l];
  sq16(p, b0 + 4, A); sq16(p, b0 + 5, B);
#pragma unroll
  for (int l = 0; l < 16; ++l) r45[l] = A[l] + B[l];
  sq16(p, b0 + 6, A); sq16(p, b0 + 7, B);
#pragma unroll
  for (int l = 0; l < 16; ++l) r67[l] = A[l] + B[l];
  float s[16];
#pragma unroll
  for (int l = 0; l < 16; ++l) s[l] = q0123[l] + (r45[l] + r67[l]);
  float t[8];
#pragma unroll
  for (int l = 0; l < 8; ++l) t[l] = s[l] + s[l + 8];
  float u[4];
#pragma unroll
  for (int l = 0; l < 4; ++l) u[l] = t[l] + t[l + 4];
  return (u[0] + u[2]) + (u[1] + u[3]);
}

__global__ __launch_bounds__(256) void vq_norms(const float* __restrict__ src,
                                                float* __restrict__ dst, int nrows) {
  const int row = blockIdx.x * blockDim.x + threadIdx.x;
  if (row >= nrows) return;
  const float4* p = reinterpret_cast<const float4*>(src + (size_t)row * DD);
  dst[row] = np_pw128_sq(p, 0) + np_pw128_sq(p, 8);
}

__global__ __launch_bounds__(256) void vq_init(unsigned* __restrict__ tmin, int n) {
  const int i = blockIdx.x * blockDim.x + threadIdx.x;
  if (i < n) tmin[i] = 0xFFFFFFFFu;
}

// ---------- bf16 helpers ----------
__device__ __forceinline__ unsigned short bf16_rne(float f) {
  unsigned u = __float_as_uint(f);
  return (unsigned short)((u + 0x7fffu + ((u >> 16) & 1u)) >> 16);
}
__device__ __forceinline__ int swz16(int row, int k) {  // r7/fallback swizzle
  return (row * 32 + k) ^ ((row & 7) << 3);
}

// ============ split kernel: fp32 -> hi bf16, PRE-SWIZZLED tile image (r9-proven) ============
__global__ __launch_bounds__(256) void vq_split_hi(const float* __restrict__ src,
                                                   unsigned short* __restrict__ hi) {
  const int i = blockIdx.x * blockDim.x + threadIdx.x;  // 8-float group index
  const float4 v0 = reinterpret_cast<const float4*>(src)[2 * i];
  const float4 v1 = reinterpret_cast<const float4*>(src)[2 * i + 1];
  const float f[8] = {v0.x, v0.y, v0.z, v0.w, v1.x, v1.y, v1.z, v1.w};
  unsigned hw[4];
#pragma unroll
  for (int j = 0; j < 4; ++j)
    hw[j] = (unsigned)bf16_rne(f[2 * j]) | ((unsigned)bf16_rne(f[2 * j + 1]) << 16);
  const int e0 = i * 8;
  const int row = e0 >> 8, d0 = e0 & 255;
  const int dcb = d0 >> 5, k = d0 & 31, chunk = k >> 3;
  const int r = row & 127, rb = row >> 7;
  const int cs = chunk ^ ((r >> 1) & 3);
  reinterpret_cast<uint4*>(hi)[(size_t)(rb * 8 + dcb) * 512 + r * 4 + cs] =
      make_uint4(hw[0], hw[1], hw[2], hw[3]);
}

// ============ x-resident MFMA pass: 1 block/CU, c streamed through dbuf ============
// Wave tile 64x64 (4x4 frags). A-frags (x) hoisted to registers for ALL 8 dc8
// (static indices only). Operands SWAPPED vs r9: acc = mfma(c_frag, x_frag)
// -> D[k-local = 4*hi+j][x-local = lane&15]; dots bitwise identical, group-min
// needs only 3 in-lane fmin + shfl_xor(16,32).
__global__ __launch_bounds__(256, 1) void vq_mfma3(const unsigned short* __restrict__ xh,
                                                   const unsigned short* __restrict__ ch,
                                                   const float* __restrict__ xn,
                                                   const float* __restrict__ cn,
                                                   unsigned* __restrict__ tmin16) {
  __shared__ __align__(16) unsigned short sX[8 * 4096];  // 64 KB x image (8 dc8 tiles)
  __shared__ __align__(16) unsigned short sC[2][4096];   // 2 x 8 KB c double-buffer

  const int tid = threadIdx.x;
  const int lane = tid & 63;
  const int w = tid >> 6;
  const int wm = w >> 1, wn = w & 1;
  const int by = blockIdx.x;
  const int row0 = by * 128;

  const int r = lane & 15, hi = lane >> 4;
  const int fo = (hi ^ ((r >> 1) & 3)) * 8;  // pre-swizzled chunk offset (u16)

  // ---- prologue: stage x image (64 KB) + c tile 0 (8 KB) ----
  const unsigned short* xsrc = xh + (size_t)by * (8 * 4096);
#pragma unroll
  for (int j = 0; j < 16; ++j) {
    const int seg = j * 4 + w;
    gload16(sX + seg * 512, xsrc + seg * 512 + lane * 8);
  }
#pragma unroll
  for (int j = 0; j < 2; ++j) {
    const int seg = w * 2 + j;
    gload16(&sC[0][seg * 512], ch + seg * 512 + lane * 8);
  }
  asm volatile("s_waitcnt vmcnt(0)" ::: "memory");
  __syncthreads();

  // ---- hoist all A-fragments (x) into registers: fx[dc8][m], static indices ----
  short8 fx[8][4];
#pragma unroll
  for (int d8 = 0; d8 < 8; ++d8)
#pragma unroll
    for (int m = 0; m < 4; ++m)
      fx[d8][m] = *reinterpret_cast<const short8*>(
          &sX[d8 * 4096 + (wm * 64 + m * 16 + r) * 32 + fo]);

  float xnv[4];
#pragma unroll
  for (int m = 0; m < 4; ++m) xnv[m] = xn[row0 + wm * 64 + m * 16 + r];

  for (int bx = 0; bx < 32; ++bx) {
    f32x4 acc[4][4];
#pragma unroll
    for (int m = 0; m < 4; ++m)
#pragma unroll
      for (int n = 0; n < 4; ++n) acc[m][n] = (f32x4)0.f;

#pragma unroll
    for (int d8 = 0; d8 < 8; ++d8) {
      // stage next c tile (t+1) into the other buffer
      const int tn = bx * 8 + d8 + 1;
      if (tn < 256) {
        const unsigned short* csrc = ch + (size_t)tn * 4096;
#pragma unroll
        for (int j = 0; j < 2; ++j) {
          const int seg = w * 2 + j;
          gload16(&sC[(d8 + 1) & 1][seg * 512], csrc + seg * 512 + lane * 8);
        }
      }
      // B-side c-frags from current buffer
      short8 fc[4];
#pragma unroll
      for (int n = 0; n < 4; ++n)
        fc[n] = *reinterpret_cast<const short8*>(
            &sC[d8 & 1][(wn * 64 + n * 16 + r) * 32 + fo]);
      // swapped-operand MFMA: D[k][x]
#pragma unroll
      for (int m = 0; m < 4; ++m)
#pragma unroll
        for (int n = 0; n < 4; ++n)
          acc[m][n] = __builtin_amdgcn_mfma_f32_16x16x32_bf16(fc[n], fx[d8][m], acc[m][n], 0, 0, 0);

      asm volatile("s_waitcnt vmcnt(0)" ::: "memory");
      __syncthreads();
    }

    // ---- epilogue per c-block: per-(row,16k-group) min, transposed layout ----
    // acc[m][n][j] = dot(x[row0+wm*64+m*16+r], c[bx*128+wn*64+n*16+4*hi+j])
#pragma unroll
    for (int n = 0; n < 4; ++n) {
      const float4 cnf4 = *reinterpret_cast<const float4*>(cn + bx * 128 + wn * 64 + n * 16 + hi * 4);
      const float cj[4] = {cnf4.x, cnf4.y, cnf4.z, cnf4.w};
      const int g = bx * 8 + wn * 4 + n;
#pragma unroll
      for (int m = 0; m < 4; ++m) {
        float v = INFINITY;
#pragma unroll
        for (int j = 0; j < 4; ++j) {
          const float A = xnv[m] + cj[j];                      // fl(xn + cn)
          const float p = fmaf(-2.f, acc[m][n][j], A - xnv[m]);  // (A-xn) exact (Sterbenz)
          v = fminf(v, p);
        }
        v = fminf(v, __shfl_xor(v, 16));
        v = fminf(v, __shfl_xor(v, 32));
        if (lane < 16)
          tmin16[(size_t)(row0 + wm * 64 + m * 16 + r) * 256 + g] = mono(v);
      }
    }
  }
}

// ============ exact rescore + fused gather/STE output ============
// r9-proven candidate logic; winner row written directly (saves vq_out launch).
__global__ __launch_bounds__(256) void vq_rescore_out(const float* __restrict__ x,
                                                      const float* __restrict__ cb,
                                                      const float* __restrict__ xn,
                                                      const float* __restrict__ cn,
                                                      const unsigned* __restrict__ tmin16,
                                                      float* __restrict__ out) {
  __shared__ __align__(16) float4 lds4[4 * (16 * 64 + 64)];  // 68 KB
  const int lane = threadIdx.x & 63;
  const int wv = threadIdx.x >> 6;
  const int row = blockIdx.x * 4 + wv;
  float4* cbuf = lds4 + wv * (16 * 64 + 64);
  float4* xbuf = cbuf + 16 * 64;

  xbuf[lane] = *reinterpret_cast<const float4*>(x + (size_t)row * DD + lane * 4);

  unsigned tv[4];
#pragma unroll
  for (int c = 0; c < 4; ++c) tv[c] = tmin16[(size_t)row * 256 + c * 64 + lane];
  unsigned mv = min(min(tv[0], tv[1]), min(tv[2], tv[3]));
#pragma unroll
  for (int off = 32; off; off >>= 1) mv = min(mv, (unsigned)__shfl_xor((int)mv, off));
  const float xnr = xn[row];
  // W = ulp-cover + 1-term bf16 GEMM error margin (r9-proven)
  const unsigned tq = mono(unmono(mv) + (xnr * 3e-7f + 2e-4f));

  unsigned long long best = ~0ull;
#pragma unroll 1
  for (int c = 0; c < 4; ++c) {
    unsigned long long qm = __ballot(tv[c] <= tq);
    while (qm) {
      const int s = __ffsll(qm) - 1;
      qm &= qm - 1;
      const int g = c * 64 + s;
#pragma unroll
      for (int it = 0; it < 4; ++it) {
        const int krow = it * 4 + (lane >> 4);
        const float4* src = reinterpret_cast<const float4*>(cb + (size_t)(g * 16 + krow) * DD);
#pragma unroll
        for (int q = 0; q < 4; ++q) {
          const int chk = (lane & 15) + q * 16;
          cbuf[krow * 64 + (chk ^ krow)] = src[chk];
        }
      }
      const int rr = lane & 15;
      float dot = 0.f;
#pragma unroll 8
      for (int cch = 0; cch < 64; ++cch) {
        const float4 cv = cbuf[rr * 64 + (cch ^ rr)];
        const float4 xv = xbuf[cch];
        dot = fmaf(xv.x, cv.x, dot);
        dot = fmaf(xv.y, cv.y, dot);
        dot = fmaf(xv.z, cv.z, dot);
        dot = fmaf(xv.w, cv.w, dot);
      }
      const int k = g * 16 + rr;
      const float A = xnr + cn[k];
      const float dist = fmaf(-2.f, dot, A);  // == fl(A - 2*dot), 2*dot exact
      const unsigned long long cand = ((unsigned long long)mono(dist) << 32) | (unsigned)k;
      best = best < cand ? best : cand;
    }
  }
#pragma unroll
  for (int off = 32; off; off >>= 1) {
    const unsigned long long o = __shfl_xor(best, off);
    best = best < o ? best : o;
  }
  // fused gather + STE write (all lanes have the winner)
  const int k = (int)(best & 0xffffffffu);
  const float4 cv = *reinterpret_cast<const float4*>(cb + (size_t)k * DD + lane * 4);
  const float4 xv = xbuf[lane];
  float4 o;
  o.x = xv.x + (cv.x - xv.x);
  o.y = xv.y + (cv.y - xv.y);
  o.z = xv.z + (cv.z - xv.z);
  o.w = xv.w + (cv.w - xv.w);
  *reinterpret_cast<float4*>(out + (size_t)row * DD + lane * 4) = o;
}

// ================== round-7 fallback kernels (proven) ==================
__global__ __launch_bounds__(256) void vq_mfma(const float* __restrict__ x,
                                               const float* __restrict__ cb,
                                               const float* __restrict__ xn,
                                               const float* __restrict__ cn,
                                               unsigned* __restrict__ tmin) {
  __shared__ __align__(16) unsigned short sXH[128 * 32];
  __shared__ __align__(16) unsigned short sXL[128 * 32];
  __shared__ __align__(16) unsigned short sCH[128 * 32];
  __shared__ __align__(16) unsigned short sCL[128 * 32];

  const int tid = threadIdx.x;
  const int lane = tid & 63;
  const int wid = tid >> 6;
  const int wm = wid >> 1, wn = wid & 1;
  const int row0 = blockIdx.x * 128;
  const int kc0 = blockIdx.y * 128;
  const int srow = tid >> 1;
  const int sh = (tid & 1) * 16;

  f32x4 acc[4][4];
#pragma unroll
  for (int m = 0; m < 4; ++m)
#pragma unroll
    for (int n = 0; n < 4; ++n) acc[m][n] = (f32x4)0.f;

  for (int dc = 0; dc < DD; dc += 32) {
    const float4* xg = reinterpret_cast<const float4*>(x + (size_t)(row0 + srow) * DD + dc + sh);
    const float4* cg = reinterpret_cast<const float4*>(cb + (size_t)(kc0 + srow) * DD + dc + sh);
    float fx[16], fc[16];
#pragma unroll
    for (int j = 0; j < 4; ++j) {
      const float4 v = xg[j];
      fx[4 * j] = v.x; fx[4 * j + 1] = v.y; fx[4 * j + 2] = v.z; fx[4 * j + 3] = v.w;
    }
#pragma unroll
    for (int j = 0; j < 4; ++j) {
      const float4 v = cg[j];
      fc[4 * j] = v.x; fc[4 * j + 1] = v.y; fc[4 * j + 2] = v.z; fc[4 * j + 3] = v.w;
    }
    unsigned xhw[8], xlw[8], chw[8], clw[8];
#pragma unroll
    for (int j = 0; j < 8; ++j) {
      unsigned short h0 = bf16_rne(fx[2 * j]), h1 = bf16_rne(fx[2 * j + 1]);
      float hf0 = __uint_as_float((unsigned)h0 << 16), hf1 = __uint_as_float((unsigned)h1 << 16);
      unsigned short l0 = bf16_rne(fx[2 * j] - hf0), l1 = bf16_rne(fx[2 * j + 1] - hf1);
      xhw[j] = (unsigned)h0 | ((unsigned)h1 << 16);
      xlw[j] = (unsigned)l0 | ((unsigned)l1 << 16);
      h0 = bf16_rne(fc[2 * j]); h1 = bf16_rne(fc[2 * j + 1]);
      hf0 = __uint_as_float((unsigned)h0 << 16); hf1 = __uint_as_float((unsigned)h1 << 16);
      l0 = bf16_rne(fc[2 * j] - hf0); l1 = bf16_rne(fc[2 * j + 1] - hf1);
      chw[j] = (unsigned)h0 | ((unsigned)h1 << 16);
      clw[j] = (unsigned)l0 | ((unsigned)l1 << 16);
    }
    __syncthreads();
#pragma unroll
    for (int half = 0; half < 2; ++half) {
      const int off = swz16(srow, sh + half * 8);
      *reinterpret_cast<uint4*>(&sXH[off]) = make_uint4(xhw[4 * half], xhw[4 * half + 1], xhw[4 * half + 2], xhw[4 * half + 3]);
      *reinterpret_cast<uint4*>(&sXL[off]) = make_uint4(xlw[4 * half], xlw[4 * half + 1], xlw[4 * half + 2], xlw[4 * half + 3]);
      *reinterpret_cast<uint4*>(&sCH[off]) = make_uint4(chw[4 * half], chw[4 * half + 1], chw[4 * half + 2], chw[4 * half + 3]);
      *reinterpret_cast<uint4*>(&sCL[off]) = make_uint4(clw[4 * half], clw[4 * half + 1], clw[4 * half + 2], clw[4 * half + 3]);
    }
    __syncthreads();

    const int kg = (lane >> 4) * 8;
    short8 fbh[4], fbl[4];
#pragma unroll
    for (int n = 0; n < 4; ++n) {
      const int off = swz16(wn * 64 + n * 16 + (lane & 15), kg);
      fbh[n] = *reinterpret_cast<const short8*>(&sCH[off]);
      fbl[n] = *reinterpret_cast<const short8*>(&sCL[off]);
    }
#pragma unroll
    for (int m = 0; m < 4; ++m) {
      const int off = swz16(wm * 64 + m * 16 + (lane & 15), kg);
      const short8 fah = *reinterpret_cast<const short8*>(&sXH[off]);
      const short8 fal = *reinterpret_cast<const short8*>(&sXL[off]);
#pragma unroll
      for (int n = 0; n < 4; ++n) {
        acc[m][n] = __builtin_amdgcn_mfma_f32_16x16x32_bf16(fah, fbh[n], acc[m][n], 0, 0, 0);
        acc[m][n] = __builtin_amdgcn_mfma_f32_16x16x32_bf16(fah, fbl[n], acc[m][n], 0, 0, 0);
        acc[m][n] = __builtin_amdgcn_mfma_f32_16x16x32_bf16(fal, fbh[n], acc[m][n], 0, 0, 0);
      }
    }
  }

  const int lr = lane >> 4, lc = lane & 15;
  const int tile = blockIdx.y * 2 + wn;
#pragma unroll
  for (int m = 0; m < 4; ++m) {
    float xnv[4];
#pragma unroll
    for (int j = 0; j < 4; ++j) xnv[j] = xn[row0 + wm * 64 + m * 16 + lr * 4 + j];
    float pm[4] = {INFINITY, INFINITY, INFINITY, INFINITY};
#pragma unroll
    for (int n = 0; n < 4; ++n) {
      const float cnv = cn[kc0 + wn * 64 + n * 16 + lc];
#pragma unroll
      for (int j = 0; j < 4; ++j) {
        const float A = xnv[j] + cnv;
        const float p = fmaf(-2.f, acc[m][n][j], A - xnv[j]);
        pm[j] = fminf(pm[j], p);
      }
    }
#pragma unroll
    for (int off = 1; off < 16; off <<= 1) {
#pragma unroll
      for (int j = 0; j < 4; ++j) pm[j] = fminf(pm[j], __shfl_xor(pm[j], off));
    }
    if (lc == 0) {
#pragma unroll
      for (int j = 0; j < 4; ++j) {
        const int row = row0 + wm * 64 + m * 16 + lr * 4 + j;
        atomicMin(&tmin[(size_t)row * 64 + tile], mono(pm[j]));
      }
    }
  }
}

__global__ __launch_bounds__(256) void vq_rescore(const float* __restrict__ x,
                                                  const float* __restrict__ cb,
                                                  const float* __restrict__ xn,
                                                  const float* __restrict__ cn,
                                                  const unsigned* __restrict__ tmin,
                                                  int* __restrict__ inds) {
  const int lane = threadIdx.x & 63;
  const int row = blockIdx.x * 4 + (threadIdx.x >> 6);
  const unsigned tv = tmin[(size_t)row * 64 + lane];
  unsigned mv = tv;
#pragma unroll
  for (int off = 32; off; off >>= 1) mv = min(mv, (unsigned)__shfl_xor((int)mv, off));
  const float xnr = xn[row];
  const float thresh = unmono(mv) + (xnr * 3e-7f + 4e-6f);
  const unsigned tq = mono(thresh);
  unsigned long long qmask = __ballot(tv <= tq);

  const float* xp = x + (size_t)row * DD;
  unsigned long long best = ~0ull;
  while (qmask) {
    const int s = __ffsll(qmask) - 1;
    qmask &= qmask - 1;
    const int k = s * 64 + lane;
    const float* cp = cb + (size_t)k * DD;
    float dot = 0.f;
#pragma unroll 8
    for (int d = 0; d < DD; ++d) dot = fmaf(xp[d], cp[d], dot);
    const float A = xnr + cn[k];
    const float dist = fmaf(-2.f, dot, A);
    const unsigned long long cand = ((unsigned long long)mono(dist) << 32) | (unsigned)k;
    best = best < cand ? best : cand;
  }
#pragma unroll
  for (int off = 32; off; off >>= 1) {
    const unsigned long long o = __shfl_xor(best, off);
    best = best < o ? best : o;
  }
  if (lane == 0) inds[row] = (int)(best & 0xffffffffu);
}

__global__ __launch_bounds__(256) void vq_out(const float* __restrict__ x,
                                              const float* __restrict__ cb,
                                              const int* __restrict__ inds,
                                              float* __restrict__ out) {
  const int w = (blockIdx.x * blockDim.x + threadIdx.x) >> 6;
  const int lane = threadIdx.x & 63;
  if (w >= NN) return;
  const int k = inds[w];
  const float4 xv = *reinterpret_cast<const float4*>(x + (size_t)w * DD + lane * 4);
  const float4 cv = *reinterpret_cast<const float4*>(cb + (size_t)k * DD + lane * 4);
  float4 o;
  o.x = xv.x + (cv.x - xv.x);
  o.y = xv.y + (cv.y - xv.y);
  o.z = xv.z + (cv.z - xv.z);
  o.w = xv.w + (cv.w - xv.w);
  *reinterpret_cast<float4*>(out + (size_t)w * DD + lane * 4) = o;
}

extern "C" void kernel_launch(void* const* d_in, const int* in_sizes, int n_in,
                              void* d_out, int out_size, void* d_ws, size_t ws_size,
                              hipStream_t stream) {
  const float* x = (const float*)d_in[0];
  const float* cb = (const float*)d_in[1];
  float* out = (float*)d_out;
  char* ws = (char*)d_ws;

  float* xn = (float*)ws;
  float* cn = (float*)(ws + 131072);
  constexpr size_t BASE = 147456;

  // fast-path layout: xh 16MB | ch 2MB | tmin16 32MB (+slack)
  constexpr size_t XH_OFF = BASE;
  constexpr size_t CH_OFF = XH_OFF + (size_t)NN * DD * 2;
  constexpr size_t T16_OFF = CH_OFF + (size_t)KK * DD * 2;
  constexpr size_t INDS_OFF = T16_OFF + (size_t)NN * 256 * 4;
  constexpr size_t NEED_FAST = INDS_OFF + (size_t)NN * 4;  // ~50.6MB (same gate as r9)

  if (ws_size >= NEED_FAST) {
    unsigned short* xh = (unsigned short*)(ws + XH_OFF);
    unsigned short* ch = (unsigned short*)(ws + CH_OFF);
    unsigned* tmin16 = (unsigned*)(ws + T16_OFF);

    vq_norms<<<NN / 256, 256, 0, stream>>>(x, xn, NN);
    vq_norms<<<KK / 256, 256, 0, stream>>>(cb, cn, KK);
    vq_split_hi<<<(NN * DD / 8) / 256, 256, 0, stream>>>(x, xh);
    vq_split_hi<<<(KK * DD / 8) / 256, 256, 0, stream>>>(cb, ch);
    vq_mfma3<<<NN / 128, 256, 0, stream>>>(xh, ch, xn, cn, tmin16);
    vq_rescore_out<<<NN / 4, 256, 0, stream>>>(x, cb, xn, cn, tmin16, out);
  } else {
    // round-7 fallback (proven)
    unsigned* tmin = (unsigned*)(ws + BASE);
    int* inds = (int*)(ws + BASE + (size_t)NN * 64 * 4);

    vq_init<<<(NN * 64) / 256, 256, 0, stream>>>(tmin, NN * 64);
    vq_norms<<<NN / 256, 256, 0, stream>>>(x, xn, NN);
    vq_norms<<<KK / 256, 256, 0, stream>>>(cb, cn, KK);
    dim3 mgrid(NN / 128, KK / 128);
    vq_mfma<<<mgrid, 256, 0, stream>>>(x, cb, xn, cn, tmin);
    vq_rescore<<<NN / 4, 256, 0, stream>>>(x, cb, xn, cn, tmin, inds);
    vq_out<<<NN / 4, 256, 0, stream>>>(x, cb, inds, out);
  }
}

// Round 11
// 284.973 us; speedup vs baseline: 1.1273x; 1.1273x over previous
//
#include <hip/hip_runtime.h>
#include <cstdint>
#include <math.h>

constexpr int NN = 32768;
constexpr int KK = 4096;
constexpr int DD = 256;

typedef __attribute__((ext_vector_type(8))) short short8;
typedef __attribute__((ext_vector_type(4))) float f32x4;

// ---------- monotone float<->u32 (order-preserving incl. negatives) ----------
__device__ __forceinline__ unsigned mono(float v) {
  unsigned u = __float_as_uint(v);
  return (u & 0x80000000u) ? ~u : (u | 0x80000000u);
}
__device__ __forceinline__ float unmono(unsigned u) {
  u = (u & 0x80000000u) ? (u & 0x7fffffffu) : ~u;
  return __uint_as_float(u);
}

// ============ numpy-replica row sum-of-squares (verified bit-exact r2) ============
__device__ __forceinline__ void sq16(const float4* __restrict__ p, int b, float q[16]) {
#pragma unroll
  for (int j = 0; j < 4; ++j) {
    const float4 v = p[b * 4 + j];
    q[4 * j + 0] = v.x * v.x;
    q[4 * j + 1] = v.y * v.y;
    q[4 * j + 2] = v.z * v.z;
    q[4 * j + 3] = v.w * v.w;
  }
}
__device__ __forceinline__ float np_pw128_sq(const float4* __restrict__ p, int b0) {
  float A[16], B[16], r01[16], r23[16], q0123[16], r45[16], r67[16];
  sq16(p, b0 + 0, A); sq16(p, b0 + 1, B);
#pragma unroll
  for (int l = 0; l < 16; ++l) r01[l] = A[l] + B[l];
  sq16(p, b0 + 2, A); sq16(p, b0 + 3, B);
#pragma unroll
  for (int l = 0; l < 16; ++l) r23[l] = A[l] + B[l];
#pragma unroll
  for (int l = 0; l < 16; ++l) q0123[l] = r01[l] + r23[l];
  sq16(p, b0 + 4, A); sq16(p, b0 + 5, B);
#pragma unroll
  for (int l = 0; l < 16; ++l) r45[l] = A[l] + B[l];
  sq16(p, b0 + 6, A); sq16(p, b0 + 7, B);
#pragma unroll
  for (int l = 0; l < 16; ++l) r67[l] = A[l] + B[l];
  float s[16];
#pragma unroll
  for (int l = 0; l < 16; ++l) s[l] = q0123[l] + (r45[l] + r67[l]);
  float t[8];
#pragma unroll
  for (int l = 0; l < 8; ++l) t[l] = s[l] + s[l + 8];
  float u[4];
#pragma unroll
  for (int l = 0; l < 4; ++l) u[l] = t[l] + t[l + 4];
  return (u[0] + u[2]) + (u[1] + u[3]);
}

__global__ __launch_bounds__(256) void vq_norms(const float* __restrict__ src,
                                                float* __restrict__ dst, int nrows) {
  const int row = blockIdx.x * blockDim.x + threadIdx.x;
  if (row >= nrows) return;
  const float4* p = reinterpret_cast<const float4*>(src + (size_t)row * DD);
  dst[row] = np_pw128_sq(p, 0) + np_pw128_sq(p, 8);
}

__global__ __launch_bounds__(256) void vq_init(unsigned* __restrict__ tmin, int n) {
  const int i = blockIdx.x * blockDim.x + threadIdx.x;
  if (i < n) tmin[i] = 0xFFFFFFFFu;
}

// ---------- bf16 helpers ----------
__device__ __forceinline__ unsigned short bf16_rne(float f) {
  unsigned u = __float_as_uint(f);
  return (unsigned short)((u + 0x7fffu + ((u >> 16) & 1u)) >> 16);
}
__device__ __forceinline__ int swz16(int row, int k) {  // fallback-kernel swizzle
  return (row * 32 + k) ^ ((row & 7) << 3);
}

// ============ split kernel: fp32 -> hi bf16, PRE-SWIZZLED tile image (r9-proven) ============
// Per (rowblk, dcblk): 8KB block [128 rows][4 chunks of 16B], chunk' = chunk ^ ((row>>1)&3).
__global__ __launch_bounds__(256) void vq_split_hi(const float* __restrict__ src,
                                                   unsigned short* __restrict__ hi) {
  const int i = blockIdx.x * blockDim.x + threadIdx.x;  // 8-float group index
  const float4 v0 = reinterpret_cast<const float4*>(src)[2 * i];
  const float4 v1 = reinterpret_cast<const float4*>(src)[2 * i + 1];
  const float f[8] = {v0.x, v0.y, v0.z, v0.w, v1.x, v1.y, v1.z, v1.w};
  unsigned hw[4];
#pragma unroll
  for (int j = 0; j < 4; ++j)
    hw[j] = (unsigned)bf16_rne(f[2 * j]) | ((unsigned)bf16_rne(f[2 * j + 1]) << 16);
  const int e0 = i * 8;
  const int row = e0 >> 8, d0 = e0 & 255;
  const int dcb = d0 >> 5, k = d0 & 31, chunk = k >> 3;
  const int r = row & 127, rb = row >> 7;
  const int cs = chunk ^ ((r >> 1) & 3);
  reinterpret_cast<uint4*>(hi)[(size_t)(rb * 8 + dcb) * 512 + r * 4 + cs] =
      make_uint4(hw[0], hw[1], hw[2], hw[3]);
}

// ============ barrier-free MFMA pass: frags loaded global->VGPR directly ============
// Pre-swizzled image => one global_load_dwordx4 per 16B frag; 64 lanes of a frag
// load cover a contiguous 1KB (perfect coalescing). x-frags hoisted for all d8;
// c-frags ping-pong (fcA/fcB, static names only). No LDS, no barriers, no manual
// waitcnt: compiler-managed counted vmcnt. Numerics bit-identical to r9/r10
// (same values, same ascending-d8 MFMA order, same epilogue).
__global__ __launch_bounds__(256, 1) void vq_mfma5(const unsigned short* __restrict__ xh,
                                                   const unsigned short* __restrict__ ch,
                                                   const float* __restrict__ xn,
                                                   const float* __restrict__ cn,
                                                   unsigned* __restrict__ tmin16) {
  const int tid = threadIdx.x;
  const int lane = tid & 63;
  const int w = tid >> 6;
  const int wm = w >> 1, wn = w & 1;
  const int by = blockIdx.x;
  const int row0 = by * 128;

  const int r = lane & 15, hi = lane >> 4;
  const int fo = (hi ^ ((r >> 1) & 3)) * 8;  // swizzled 16B-chunk offset (u16 units)

  // ---- hoist all A-frags (x): 8 d8 x 4 m, direct from the pre-swizzled image ----
  const unsigned short* xb = xh + (size_t)by * (8 * 4096);
  short8 fx[8][4];
#pragma unroll
  for (int d8 = 0; d8 < 8; ++d8)
#pragma unroll
    for (int m = 0; m < 4; ++m)
      fx[d8][m] = *reinterpret_cast<const short8*>(
          xb + (size_t)d8 * 4096 + (wm * 64 + m * 16 + r) * 32 + fo);

  float xnv[4];
#pragma unroll
  for (int m = 0; m < 4; ++m) xnv[m] = xn[row0 + wm * 64 + m * 16 + r];

  // ---- prime c-frag ping-pong with tile 0 ----
  short8 fcA[4], fcB[4];
#pragma unroll
  for (int n = 0; n < 4; ++n)
    fcA[n] = *reinterpret_cast<const short8*>(ch + (wn * 64 + n * 16 + r) * 32 + fo);

// one K-step: load frags of tile t+1 into NXT, MFMA with CUR (tile t)
#define VQ_STEP(CUR, NXT, D8)                                                        \
  {                                                                                  \
    const int tn_ = (bx * 8 + (D8) + 1) & 255;                                       \
    const unsigned short* ct_ = ch + (size_t)tn_ * 4096;                             \
    _Pragma("unroll") for (int n = 0; n < 4; ++n)                                    \
        NXT[n] = *reinterpret_cast<const short8*>(ct_ + (wn * 64 + n * 16 + r) * 32 + fo); \
    _Pragma("unroll") for (int m = 0; m < 4; ++m)                                    \
        _Pragma("unroll") for (int n = 0; n < 4; ++n)                                \
            acc[m][n] = __builtin_amdgcn_mfma_f32_16x16x32_bf16(CUR[n], fx[(D8)][m], \
                                                                acc[m][n], 0, 0, 0); \
  }

  for (int bx = 0; bx < 32; ++bx) {
    // prefetch cn for this bx's epilogue (hidden under the 8 MFMA steps)
    float4 cnf[4];
#pragma unroll
    for (int n = 0; n < 4; ++n)
      cnf[n] = *reinterpret_cast<const float4*>(cn + bx * 128 + wn * 64 + n * 16 + hi * 4);

    f32x4 acc[4][4];
#pragma unroll
    for (int m = 0; m < 4; ++m)
#pragma unroll
      for (int n = 0; n < 4; ++n) acc[m][n] = (f32x4)0.f;

    VQ_STEP(fcA, fcB, 0)
    VQ_STEP(fcB, fcA, 1)
    VQ_STEP(fcA, fcB, 2)
    VQ_STEP(fcB, fcA, 3)
    VQ_STEP(fcA, fcB, 4)
    VQ_STEP(fcB, fcA, 5)
    VQ_STEP(fcA, fcB, 6)
    VQ_STEP(fcB, fcA, 7)  // loads tile (bx+1)*8+0 into fcA -> pipeline crosses bx

    // ---- epilogue (r10-proven, bit-identical): per-(row,16k-group) min ----
    // acc[m][n][j] = dot(x[row0+wm*64+m*16+r], c[bx*128+wn*64+n*16+4*hi+j])
#pragma unroll
    for (int n = 0; n < 4; ++n) {
      const float cj[4] = {cnf[n].x, cnf[n].y, cnf[n].z, cnf[n].w};
      const int g = bx * 8 + wn * 4 + n;
#pragma unroll
      for (int m = 0; m < 4; ++m) {
        float v = INFINITY;
#pragma unroll
        for (int j = 0; j < 4; ++j) {
          const float A = xnv[m] + cj[j];                        // fl(xn + cn)
          const float p = fmaf(-2.f, acc[m][n][j], A - xnv[m]);  // (A-xn) exact (Sterbenz)
          v = fminf(v, p);
        }
        v = fminf(v, __shfl_xor(v, 16));
        v = fminf(v, __shfl_xor(v, 32));
        if (lane < 16)
          tmin16[(size_t)(row0 + wm * 64 + m * 16 + r) * 256 + g] = mono(v);
      }
    }
  }
#undef VQ_STEP
}

// ============ exact rescore + fused gather/STE output (r10-proven) ============
__global__ __launch_bounds__(256) void vq_rescore_out(const float* __restrict__ x,
                                                      const float* __restrict__ cb,
                                                      const float* __restrict__ xn,
                                                      const float* __restrict__ cn,
                                                      const unsigned* __restrict__ tmin16,
                                                      float* __restrict__ out) {
  __shared__ __align__(16) float4 lds4[4 * (16 * 64 + 64)];  // 68 KB
  const int lane = threadIdx.x & 63;
  const int wv = threadIdx.x >> 6;
  const int row = blockIdx.x * 4 + wv;
  float4* cbuf = lds4 + wv * (16 * 64 + 64);
  float4* xbuf = cbuf + 16 * 64;

  xbuf[lane] = *reinterpret_cast<const float4*>(x + (size_t)row * DD + lane * 4);

  unsigned tv[4];
#pragma unroll
  for (int c = 0; c < 4; ++c) tv[c] = tmin16[(size_t)row * 256 + c * 64 + lane];
  unsigned mv = min(min(tv[0], tv[1]), min(tv[2], tv[3]));
#pragma unroll
  for (int off = 32; off; off >>= 1) mv = min(mv, (unsigned)__shfl_xor((int)mv, off));
  const float xnr = xn[row];
  // W = ulp-cover + 1-term bf16 GEMM error margin (r9/r10-proven)
  const unsigned tq = mono(unmono(mv) + (xnr * 3e-7f + 2e-4f));

  unsigned long long best = ~0ull;
#pragma unroll 1
  for (int c = 0; c < 4; ++c) {
    unsigned long long qm = __ballot(tv[c] <= tq);
    while (qm) {
      const int s = __ffsll(qm) - 1;
      qm &= qm - 1;
      const int g = c * 64 + s;
#pragma unroll
      for (int it = 0; it < 4; ++it) {
        const int krow = it * 4 + (lane >> 4);
        const float4* src = reinterpret_cast<const float4*>(cb + (size_t)(g * 16 + krow) * DD);
#pragma unroll
        for (int q = 0; q < 4; ++q) {
          const int chk = (lane & 15) + q * 16;
          cbuf[krow * 64 + (chk ^ krow)] = src[chk];
        }
      }
      const int rr = lane & 15;
      float dot = 0.f;
#pragma unroll 8
      for (int cch = 0; cch < 64; ++cch) {
        const float4 cv = cbuf[rr * 64 + (cch ^ rr)];
        const float4 xv = xbuf[cch];
        dot = fmaf(xv.x, cv.x, dot);
        dot = fmaf(xv.y, cv.y, dot);
        dot = fmaf(xv.z, cv.z, dot);
        dot = fmaf(xv.w, cv.w, dot);
      }
      const int k = g * 16 + rr;
      const float A = xnr + cn[k];
      const float dist = fmaf(-2.f, dot, A);  // == fl(A - 2*dot), 2*dot exact
      const unsigned long long cand = ((unsigned long long)mono(dist) << 32) | (unsigned)k;
      best = best < cand ? best : cand;
    }
  }
#pragma unroll
  for (int off = 32; off; off >>= 1) {
    const unsigned long long o = __shfl_xor(best, off);
    best = best < o ? best : o;
  }
  const int k = (int)(best & 0xffffffffu);
  const float4 cv = *reinterpret_cast<const float4*>(cb + (size_t)k * DD + lane * 4);
  const float4 xv = xbuf[lane];
  float4 o;
  o.x = xv.x + (cv.x - xv.x);
  o.y = xv.y + (cv.y - xv.y);
  o.z = xv.z + (cv.z - xv.z);
  o.w = xv.w + (cv.w - xv.w);
  *reinterpret_cast<float4*>(out + (size_t)row * DD + lane * 4) = o;
}

// ================== round-7 fallback kernels (proven) ==================
__global__ __launch_bounds__(256) void vq_mfma(const float* __restrict__ x,
                                               const float* __restrict__ cb,
                                               const float* __restrict__ xn,
                                               const float* __restrict__ cn,
                                               unsigned* __restrict__ tmin) {
  __shared__ __align__(16) unsigned short sXH[128 * 32];
  __shared__ __align__(16) unsigned short sXL[128 * 32];
  __shared__ __align__(16) unsigned short sCH[128 * 32];
  __shared__ __align__(16) unsigned short sCL[128 * 32];

  const int tid = threadIdx.x;
  const int lane = tid & 63;
  const int wid = tid >> 6;
  const int wm = wid >> 1, wn = wid & 1;
  const int row0 = blockIdx.x * 128;
  const int kc0 = blockIdx.y * 128;
  const int srow = tid >> 1;
  const int sh = (tid & 1) * 16;

  f32x4 acc[4][4];
#pragma unroll
  for (int m = 0; m < 4; ++m)
#pragma unroll
    for (int n = 0; n < 4; ++n) acc[m][n] = (f32x4)0.f;

  for (int dc = 0; dc < DD; dc += 32) {
    const float4* xg = reinterpret_cast<const float4*>(x + (size_t)(row0 + srow) * DD + dc + sh);
    const float4* cg = reinterpret_cast<const float4*>(cb + (size_t)(kc0 + srow) * DD + dc + sh);
    float fx[16], fc[16];
#pragma unroll
    for (int j = 0; j < 4; ++j) {
      const float4 v = xg[j];
      fx[4 * j] = v.x; fx[4 * j + 1] = v.y; fx[4 * j + 2] = v.z; fx[4 * j + 3] = v.w;
    }
#pragma unroll
    for (int j = 0; j < 4; ++j) {
      const float4 v = cg[j];
      fc[4 * j] = v.x; fc[4 * j + 1] = v.y; fc[4 * j + 2] = v.z; fc[4 * j + 3] = v.w;
    }
    unsigned xhw[8], xlw[8], chw[8], clw[8];
#pragma unroll
    for (int j = 0; j < 8; ++j) {
      unsigned short h0 = bf16_rne(fx[2 * j]), h1 = bf16_rne(fx[2 * j + 1]);
      float hf0 = __uint_as_float((unsigned)h0 << 16), hf1 = __uint_as_float((unsigned)h1 << 16);
      unsigned short l0 = bf16_rne(fx[2 * j] - hf0), l1 = bf16_rne(fx[2 * j + 1] - hf1);
      xhw[j] = (unsigned)h0 | ((unsigned)h1 << 16);
      xlw[j] = (unsigned)l0 | ((unsigned)l1 << 16);
      h0 = bf16_rne(fc[2 * j]); h1 = bf16_rne(fc[2 * j + 1]);
      hf0 = __uint_as_float((unsigned)h0 << 16); hf1 = __uint_as_float((unsigned)h1 << 16);
      l0 = bf16_rne(fc[2 * j] - hf0); l1 = bf16_rne(fc[2 * j + 1] - hf1);
      chw[j] = (unsigned)h0 | ((unsigned)h1 << 16);
      clw[j] = (unsigned)l0 | ((unsigned)l1 << 16);
    }
    __syncthreads();
#pragma unroll
    for (int half = 0; half < 2; ++half) {
      const int off = swz16(srow, sh + half * 8);
      *reinterpret_cast<uint4*>(&sXH[off]) = make_uint4(xhw[4 * half], xhw[4 * half + 1], xhw[4 * half + 2], xhw[4 * half + 3]);
      *reinterpret_cast<uint4*>(&sXL[off]) = make_uint4(xlw[4 * half], xlw[4 * half + 1], xlw[4 * half + 2], xlw[4 * half + 3]);
      *reinterpret_cast<uint4*>(&sCH[off]) = make_uint4(chw[4 * half], chw[4 * half + 1], chw[4 * half + 2], chw[4 * half + 3]);
      *reinterpret_cast<uint4*>(&sCL[off]) = make_uint4(clw[4 * half], clw[4 * half + 1], clw[4 * half + 2], clw[4 * half + 3]);
    }
    __syncthreads();

    const int kg = (lane >> 4) * 8;
    short8 fbh[4], fbl[4];
#pragma unroll
    for (int n = 0; n < 4; ++n) {
      const int off = swz16(wn * 64 + n * 16 + (lane & 15), kg);
      fbh[n] = *reinterpret_cast<const short8*>(&sCH[off]);
      fbl[n] = *reinterpret_cast<const short8*>(&sCL[off]);
    }
#pragma unroll
    for (int m = 0; m < 4; ++m) {
      const int off = swz16(wm * 64 + m * 16 + (lane & 15), kg);
      const short8 fah = *reinterpret_cast<const short8*>(&sXH[off]);
      const short8 fal = *reinterpret_cast<const short8*>(&sXL[off]);
#pragma unroll
      for (int n = 0; n < 4; ++n) {
        acc[m][n] = __builtin_amdgcn_mfma_f32_16x16x32_bf16(fah, fbh[n], acc[m][n], 0, 0, 0);
        acc[m][n] = __builtin_amdgcn_mfma_f32_16x16x32_bf16(fah, fbl[n], acc[m][n], 0, 0, 0);
        acc[m][n] = __builtin_amdgcn_mfma_f32_16x16x32_bf16(fal, fbh[n], acc[m][n], 0, 0, 0);
      }
    }
  }

  const int lr = lane >> 4, lc = lane & 15;
  const int tile = blockIdx.y * 2 + wn;
#pragma unroll
  for (int m = 0; m < 4; ++m) {
    float xnv[4];
#pragma unroll
    for (int j = 0; j < 4; ++j) xnv[j] = xn[row0 + wm * 64 + m * 16 + lr * 4 + j];
    float pm[4] = {INFINITY, INFINITY, INFINITY, INFINITY};
#pragma unroll
    for (int n = 0; n < 4; ++n) {
      const float cnv = cn[kc0 + wn * 64 + n * 16 + lc];
#pragma unroll
      for (int j = 0; j < 4; ++j) {
        const float A = xnv[j] + cnv;
        const float p = fmaf(-2.f, acc[m][n][j], A - xnv[j]);
        pm[j] = fminf(pm[j], p);
      }
    }
#pragma unroll
    for (int off = 1; off < 16; off <<= 1) {
#pragma unroll
      for (int j = 0; j < 4; ++j) pm[j] = fminf(pm[j], __shfl_xor(pm[j], off));
    }
    if (lc == 0) {
#pragma unroll
      for (int j = 0; j < 4; ++j) {
        const int row = row0 + wm * 64 + m * 16 + lr * 4 + j;
        atomicMin(&tmin[(size_t)row * 64 + tile], mono(pm[j]));
      }
    }
  }
}

__global__ __launch_bounds__(256) void vq_rescore(const float* __restrict__ x,
                                                  const float* __restrict__ cb,
                                                  const float* __restrict__ xn,
                                                  const float* __restrict__ cn,
                                                  const unsigned* __restrict__ tmin,
                                                  int* __restrict__ inds) {
  const int lane = threadIdx.x & 63;
  const int row = blockIdx.x * 4 + (threadIdx.x >> 6);
  const unsigned tv = tmin[(size_t)row * 64 + lane];
  unsigned mv = tv;
#pragma unroll
  for (int off = 32; off; off >>= 1) mv = min(mv, (unsigned)__shfl_xor((int)mv, off));
  const float xnr = xn[row];
  const float thresh = unmono(mv) + (xnr * 3e-7f + 4e-6f);
  const unsigned tq = mono(thresh);
  unsigned long long qmask = __ballot(tv <= tq);

  const float* xp = x + (size_t)row * DD;
  unsigned long long best = ~0ull;
  while (qmask) {
    const int s = __ffsll(qmask) - 1;
    qmask &= qmask - 1;
    const int k = s * 64 + lane;
    const float* cp = cb + (size_t)k * DD;
    float dot = 0.f;
#pragma unroll 8
    for (int d = 0; d < DD; ++d) dot = fmaf(xp[d], cp[d], dot);
    const float A = xnr + cn[k];
    const float dist = fmaf(-2.f, dot, A);
    const unsigned long long cand = ((unsigned long long)mono(dist) << 32) | (unsigned)k;
    best = best < cand ? best : cand;
  }
#pragma unroll
  for (int off = 32; off; off >>= 1) {
    const unsigned long long o = __shfl_xor(best, off);
    best = best < o ? best : o;
  }
  if (lane == 0) inds[row] = (int)(best & 0xffffffffu);
}

__global__ __launch_bounds__(256) void vq_out(const float* __restrict__ x,
                                              const float* __restrict__ cb,
                                              const int* __restrict__ inds,
                                              float* __restrict__ out) {
  const int w = (blockIdx.x * blockDim.x + threadIdx.x) >> 6;
  const int lane = threadIdx.x & 63;
  if (w >= NN) return;
  const int k = inds[w];
  const float4 xv = *reinterpret_cast<const float4*>(x + (size_t)w * DD + lane * 4);
  const float4 cv = *reinterpret_cast<const float4*>(cb + (size_t)k * DD + lane * 4);
  float4 o;
  o.x = xv.x + (cv.x - xv.x);
  o.y = xv.y + (cv.y - xv.y);
  o.z = xv.z + (cv.z - xv.z);
  o.w = xv.w + (cv.w - xv.w);
  *reinterpret_cast<float4*>(out + (size_t)w * DD + lane * 4) = o;
}

extern "C" void kernel_launch(void* const* d_in, const int* in_sizes, int n_in,
                              void* d_out, int out_size, void* d_ws, size_t ws_size,
                              hipStream_t stream) {
  const float* x = (const float*)d_in[0];
  const float* cb = (const float*)d_in[1];
  float* out = (float*)d_out;
  char* ws = (char*)d_ws;

  float* xn = (float*)ws;
  float* cn = (float*)(ws + 131072);
  constexpr size_t BASE = 147456;

  // fast-path layout: xh 16MB | ch 2MB | tmin16 32MB (+slack)
  constexpr size_t XH_OFF = BASE;
  constexpr size_t CH_OFF = XH_OFF + (size_t)NN * DD * 2;
  constexpr size_t T16_OFF = CH_OFF + (size_t)KK * DD * 2;
  constexpr size_t INDS_OFF = T16_OFF + (size_t)NN * 256 * 4;
  constexpr size_t NEED_FAST = INDS_OFF + (size_t)NN * 4;  // ~50.6MB (same gate as r9/r10)

  if (ws_size >= NEED_FAST) {
    unsigned short* xh = (unsigned short*)(ws + XH_OFF);
    unsigned short* ch = (unsigned short*)(ws + CH_OFF);
    unsigned* tmin16 = (unsigned*)(ws + T16_OFF);

    vq_norms<<<NN / 256, 256, 0, stream>>>(x, xn, NN);
    vq_norms<<<KK / 256, 256, 0, stream>>>(cb, cn, KK);
    vq_split_hi<<<(NN * DD / 8) / 256, 256, 0, stream>>>(x, xh);
    vq_split_hi<<<(KK * DD / 8) / 256, 256, 0, stream>>>(cb, ch);
    vq_mfma5<<<NN / 128, 256, 0, stream>>>(xh, ch, xn, cn, tmin16);
    vq_rescore_out<<<NN / 4, 256, 0, stream>>>(x, cb, xn, cn, tmin16, out);
  } else {
    // round-7 fallback (proven)
    unsigned* tmin = (unsigned*)(ws + BASE);
    int* inds = (int*)(ws + BASE + (size_t)NN * 64 * 4);

    vq_init<<<(NN * 64) / 256, 256, 0, stream>>>(tmin, NN * 64);
    vq_norms<<<NN / 256, 256, 0, stream>>>(x, xn, NN);
    vq_norms<<<KK / 256, 256, 0, stream>>>(cb, cn, KK);
    dim3 mgrid(NN / 128, KK / 128);
    vq_mfma<<<mgrid, 256, 0, stream>>>(x, cb, xn, cn, tmin);
    vq_rescore<<<NN / 4, 256, 0, stream>>>(x, cb, xn, cn, tmin, inds);
    vq_out<<<NN / 4, 256, 0, stream>>>(x, cb, inds, out);
  }
}